// Round 1
// baseline (331.086 us; speedup 1.0000x reference)
//
#include <hip/hip_runtime.h>
#include <math.h>

#define NB 256          // batch
#define XW 5048         // input row width
#define GENE 3000
#define DRUGW 2048
#define EPSF 1e-5f

// ---------- input BN: per-column stats over batch, write normalized transposed ----------
__global__ void k_in_bn(const float* __restrict__ x,
                        const float* __restrict__ gg, const float* __restrict__ eg,
                        const float* __restrict__ gd, const float* __restrict__ ed,
                        float* __restrict__ gene_t, float* __restrict__ drug_t) {
    int c = blockIdx.x;            // 0..5047
    int b = threadIdx.x;           // 0..255
    float v = x[b * XW + c];
    __shared__ float s1[256], s2[256];
    s1[b] = v; s2[b] = v * v;
    __syncthreads();
    for (int s = 128; s > 0; s >>= 1) {
        if (b < s) { s1[b] += s1[b + s]; s2[b] += s2[b + s]; }
        __syncthreads();
    }
    float mu  = s1[0] * (1.0f / 256.0f);
    float var = s2[0] * (1.0f / 256.0f) - mu * mu;
    float rs  = rsqrtf(var + EPSF);
    if (c < GENE) {
        float a = gg[c] * rs;
        gene_t[c * NB + b] = a * v + (eg[c] - a * mu);
    } else {
        int cd = c - GENE;
        float a = gd[cd] * rs;
        drug_t[cd * NB + b] = a * v + (ed[cd] - a * mu);
    }
}

// ---------- row stats on feature-major buffer: out a[f], c[f] with bn(x)=a*x+c ----------
__global__ void k_rowstats(const float* __restrict__ h_t,
                           const float* __restrict__ g, const float* __restrict__ e,
                           float* __restrict__ a, float* __restrict__ c) {
    int r = blockIdx.x;
    int b = threadIdx.x;
    float v = h_t[r * NB + b];
    __shared__ float s1[256], s2[256];
    s1[b] = v; s2[b] = v * v;
    __syncthreads();
    for (int s = 128; s > 0; s >>= 1) {
        if (b < s) { s1[b] += s1[b + s]; s2[b] += s2[b + s]; }
        __syncthreads();
    }
    if (b == 0) {
        float mu  = s1[0] * (1.0f / 256.0f);
        float var = s2[0] * (1.0f / 256.0f) - mu * mu;
        float rs  = rsqrtf(var + EPSF);
        float aa  = g[r] * rs;
        a[r] = aa;
        c[r] = e[r] - aa * mu;
    }
}

// ---------- sparse layer 0: 1500 terms, 30 gene cols each, 6 rows per term ----------
__global__ void k_splin0(const float* __restrict__ gene_t,
                         const int* __restrict__ cols0, const float* __restrict__ w0,
                         const float* __restrict__ b0, float* __restrict__ h1_t) {
    int t = blockIdx.x;            // 0..1499
    int b = threadIdx.x;
    float acc[6];
    #pragma unroll
    for (int k = 0; k < 6; k++) acc[k] = 0.f;
    int base = t * 180;            // t*30*6
    for (int i = 0; i < 30; i++) {
        int ei = base + i * 6;
        int cc = cols0[ei];        // same col for all 6 k
        float v = gene_t[cc * NB + b];
        #pragma unroll
        for (int k = 0; k < 6; k++) acc[k] += v * w0[ei + k];
    }
    #pragma unroll
    for (int k = 0; k < 6; k++)
        h1_t[(t * 6 + k) * NB + b] = tanhf(acc[k] + b0[t * 6 + k]);
}

// ---------- sparse layer 1: 400 terms, 5 children x 6x6 dense blocks ----------
__global__ void k_splin1(const float* __restrict__ h1_t,
                         const float* __restrict__ a1, const float* __restrict__ c1,
                         const int* __restrict__ cols1, const float* __restrict__ w1,
                         const float* __restrict__ b1, float* __restrict__ h2_t) {
    int o = blockIdx.x;            // 0..399
    int b = threadIdx.x;
    float acc[6];
    #pragma unroll
    for (int i = 0; i < 6; i++) acc[i] = 0.f;
    for (int pi = 0; pi < 5; pi++) {
        int qb = (o * 5 + pi) * 36;
        #pragma unroll
        for (int j = 0; j < 6; j++) {
            int cc = cols1[qb + j];                 // col for (i=0, j) == c*6+j
            float v = a1[cc] * h1_t[cc * NB + b] + c1[cc];
            #pragma unroll
            for (int i = 0; i < 6; i++) acc[i] += v * w1[qb + i * 6 + j];
        }
    }
    #pragma unroll
    for (int i = 0; i < 6; i++)
        h2_t[(o * 6 + i) * NB + b] = tanhf(acc[i] + b1[o * 6 + i]);
}

// ---------- sparse layer 2: effectively dense 24x2400, writes fbuf rows 0..23 ----------
__global__ void k_splin2(const float* __restrict__ h2_t,
                         const float* __restrict__ a2, const float* __restrict__ c2,
                         const float* __restrict__ w2, const float* __restrict__ b2,
                         float* __restrict__ fbuf) {
    int kf = blockIdx.x;           // 0..23
    int b = threadIdx.x;
    float acc = 0.f;
    for (int t = 0; t < 400; t++) {
        #pragma unroll
        for (int j = 0; j < 6; j++) {
            int cc = t * 6 + j;
            float v = a2[cc] * h2_t[cc * NB + b] + c2[cc];
            acc += v * w2[t * 144 + kf * 6 + j];
        }
    }
    fbuf[kf * NB + b] = tanhf(acc + b2[kf]);
}

// ---------- drug layer 1 (2048 -> 128), chunked partial sums ----------
__global__ void k_dense1_part(const float* __restrict__ drug_t,
                              const float* __restrict__ Wd1, float* __restrict__ part) {
    int jg = blockIdx.x >> 3;      // 0..15 (8 outputs each)
    int ch = blockIdx.x & 7;       // 0..7 (256 cols each)
    int b = threadIdx.x;
    int j0 = jg * 8;
    int c0 = ch * 256;
    float acc[8];
    #pragma unroll
    for (int jj = 0; jj < 8; jj++) acc[jj] = 0.f;
    for (int c = c0; c < c0 + 256; c++) {
        float v = drug_t[c * NB + b];
        #pragma unroll
        for (int jj = 0; jj < 8; jj++) acc[jj] += v * Wd1[(j0 + jj) * DRUGW + c];
    }
    #pragma unroll
    for (int jj = 0; jj < 8; jj++)
        part[((j0 + jj) * 8 + ch) * NB + b] = acc[jj];
}

__global__ void k_dense1_fin(const float* __restrict__ part,
                             const float* __restrict__ bd1, float* __restrict__ d1_t) {
    int j = blockIdx.x;            // 0..127
    int b = threadIdx.x;
    float acc = bd1[j];
    #pragma unroll
    for (int ch = 0; ch < 8; ch++) acc += part[(j * 8 + ch) * NB + b];
    d1_t[j * NB + b] = tanhf(acc);
}

// ---------- small dense layer with on-the-fly BN: out = tanh(bn(in) @ W.T + bias) ----------
template<int JPB>
__global__ void k_dense_small(const float* __restrict__ in_t,
                              const float* __restrict__ a, const float* __restrict__ c,
                              const float* __restrict__ W, const float* __restrict__ bias,
                              float* __restrict__ out_t, int ncols) {
    int j0 = blockIdx.x * JPB;
    int b = threadIdx.x;
    float acc[JPB];
    #pragma unroll
    for (int jj = 0; jj < JPB; jj++) acc[jj] = 0.f;
    for (int cc = 0; cc < ncols; cc++) {
        float v = a[cc] * in_t[cc * NB + b] + c[cc];
        #pragma unroll
        for (int jj = 0; jj < JPB; jj++) acc[jj] += v * W[(j0 + jj) * ncols + cc];
    }
    #pragma unroll
    for (int jj = 0; jj < JPB; jj++)
        out_t[(j0 + jj) * NB + b] = tanhf(acc[jj] + bias[j0 + jj]);
}

// ---------- head: o2 = tanh(bn(o1) @ Wa.T + ba); out = o2*Wo + bo ----------
__global__ void k_final(const float* __restrict__ o1_t,
                        const float* __restrict__ aa, const float* __restrict__ ca,
                        const float* __restrict__ Wa, const float* __restrict__ ba,
                        const float* __restrict__ Wo, const float* __restrict__ bo,
                        float* __restrict__ out) {
    int b = threadIdx.x;
    float acc = ba[0];
    #pragma unroll
    for (int j = 0; j < 64; j++)
        acc += (aa[j] * o1_t[j * NB + b] + ca[j]) * Wa[j];
    out[b] = tanhf(acc) * Wo[0] + bo[0];
}

extern "C" void kernel_launch(void* const* d_in, const int* in_sizes, int n_in,
                              void* d_out, int out_size, void* d_ws, size_t ws_size,
                              hipStream_t stream) {
    const float* x    = (const float*)d_in[0];
    const int*   cols0 = (const int*)d_in[2];
    const float* w0   = (const float*)d_in[3];
    const float* b0   = (const float*)d_in[4];
    const int*   cols1 = (const int*)d_in[6];
    const float* w1   = (const float*)d_in[7];
    const float* b1   = (const float*)d_in[8];
    const float* w2   = (const float*)d_in[11];
    const float* b2   = (const float*)d_in[12];
    const float* gg   = (const float*)d_in[13];
    const float* eg   = (const float*)d_in[14];
    const float* g1   = (const float*)d_in[15];
    const float* e1   = (const float*)d_in[16];
    const float* g2   = (const float*)d_in[17];
    const float* e2   = (const float*)d_in[18];
    const float* Wd1  = (const float*)d_in[19];
    const float* bd1  = (const float*)d_in[20];
    const float* gd1  = (const float*)d_in[21];
    const float* ed1  = (const float*)d_in[22];
    const float* Wd2  = (const float*)d_in[23];
    const float* bd2  = (const float*)d_in[24];
    const float* gd2  = (const float*)d_in[25];
    const float* ed2  = (const float*)d_in[26];
    const float* Wd3  = (const float*)d_in[27];
    const float* bd3  = (const float*)d_in[28];
    const float* gd3  = (const float*)d_in[29];
    const float* ed3  = (const float*)d_in[30];
    const float* gf   = (const float*)d_in[31];
    const float* ef   = (const float*)d_in[32];
    const float* Wf   = (const float*)d_in[33];
    const float* bf   = (const float*)d_in[34];
    const float* ga   = (const float*)d_in[35];
    const float* ea   = (const float*)d_in[36];
    const float* Wa   = (const float*)d_in[37];
    const float* ba   = (const float*)d_in[38];
    const float* Wo   = (const float*)d_in[39];
    const float* bo   = (const float*)d_in[40];
    float* out = (float*)d_out;

    float* W = (float*)d_ws;
    float* gene_t = W;                       // 3000*256
    float* drug_t = gene_t + 3000 * NB;      // 2048*256
    float* h1_t   = drug_t + 2048 * NB;      // 9000*256
    float* h2_t   = h1_t   + 9000 * NB;      // 2400*256
    float* fbuf   = h2_t   + 2400 * NB;      // 56*256
    float* d1_t   = fbuf   + 56 * NB;        // 128*256
    float* d2_t   = d1_t   + 128 * NB;       // 64*256
    float* o1_t   = d2_t   + 64 * NB;        // 64*256
    float* part   = o1_t   + 64 * NB;        // 128*8*256
    float* a1 = part + 128 * 8 * NB;         // 9000
    float* c1 = a1 + 9000;
    float* a2 = c1 + 9000;                   // 2400
    float* c2 = a2 + 2400;
    float* ad1 = c2 + 2400;                  // 128
    float* cd1 = ad1 + 128;
    float* ad2 = cd1 + 128;                  // 64
    float* cd2 = ad2 + 64;
    float* af = cd2 + 64;                    // 56
    float* cf = af + 56;
    float* aah = cf + 56;                    // 64
    float* cah = aah + 64;

    // gene + drug input BN (normalized, transposed to feature-major)
    k_in_bn<<<XW, 256, 0, stream>>>(x, gg, eg, gd1, ed1, gene_t, drug_t);

    // gene path
    k_splin0<<<1500, 256, 0, stream>>>(gene_t, cols0, w0, b0, h1_t);
    k_rowstats<<<9000, 256, 0, stream>>>(h1_t, g1, e1, a1, c1);
    k_splin1<<<400, 256, 0, stream>>>(h1_t, a1, c1, cols1, w1, b1, h2_t);
    k_rowstats<<<2400, 256, 0, stream>>>(h2_t, g2, e2, a2, c2);
    k_splin2<<<24, 256, 0, stream>>>(h2_t, a2, c2, w2, b2, fbuf);   // fbuf rows 0..23

    // drug path
    k_dense1_part<<<128, 256, 0, stream>>>(drug_t, Wd1, part);
    k_dense1_fin<<<128, 256, 0, stream>>>(part, bd1, d1_t);
    k_rowstats<<<128, 256, 0, stream>>>(d1_t, gd2, ed2, ad1, cd1);
    k_dense_small<8><<<8, 256, 0, stream>>>(d1_t, ad1, cd1, Wd2, bd2, d2_t, 128);
    k_rowstats<<<64, 256, 0, stream>>>(d2_t, gd3, ed3, ad2, cd2);
    k_dense_small<8><<<4, 256, 0, stream>>>(d2_t, ad2, cd2, Wd3, bd3, fbuf + 24 * NB, 64);

    // head
    k_rowstats<<<56, 256, 0, stream>>>(fbuf, gf, ef, af, cf);
    k_dense_small<8><<<8, 256, 0, stream>>>(fbuf, af, cf, Wf, bf, o1_t, 56);
    k_rowstats<<<64, 256, 0, stream>>>(o1_t, ga, ea, aah, cah);
    k_final<<<1, 256, 0, stream>>>(o1_t, aah, cah, Wa, ba, Wo, bo, out);
}

// Round 2
// 148.917 us; speedup vs baseline: 2.2233x; 2.2233x over previous
//
#include <hip/hip_runtime.h>
#include <math.h>

#define NB 256          // batch
#define XW 5048         // input row width
#define GENE 3000
#define DRUGW 2048
#define EPSF 1e-5f

// ---------------------------------------------------------------------------
// Epilogue helper: given per-thread values v[NR] for rows r0..r0+NR-1 (thread b
// = batch index), compute batch mean/var per row, fold BN (g,e pre-offset to
// row base), and write NORMALIZED values to out_t (pre-offset to row base).
// ---------------------------------------------------------------------------
template<int NR>
__device__ __forceinline__ void bn_fold_write(float (&v)[NR], int b,
        const float* __restrict__ g, const float* __restrict__ e,
        float* __restrict__ out_t) {
    __shared__ float sred[NR][4][2];
    __shared__ float s_ac[2][NR];
    int lane = b & 63, wv = b >> 6;
    float s1[NR], s2[NR];
    #pragma unroll
    for (int k = 0; k < NR; k++) { s1[k] = v[k]; s2[k] = v[k] * v[k]; }
    #pragma unroll
    for (int off = 32; off >= 1; off >>= 1) {
        #pragma unroll
        for (int k = 0; k < NR; k++) {
            s1[k] += __shfl_xor(s1[k], off);
            s2[k] += __shfl_xor(s2[k], off);
        }
    }
    if (lane == 0) {
        #pragma unroll
        for (int k = 0; k < NR; k++) { sred[k][wv][0] = s1[k]; sred[k][wv][1] = s2[k]; }
    }
    __syncthreads();
    if (b < NR) {
        float t1 = sred[b][0][0] + sred[b][1][0] + sred[b][2][0] + sred[b][3][0];
        float t2 = sred[b][0][1] + sred[b][1][1] + sred[b][2][1] + sred[b][3][1];
        float mu  = t1 * (1.0f / 256.0f);
        float var = t2 * (1.0f / 256.0f) - mu * mu;
        float rs  = rsqrtf(var + EPSF);
        float aa  = g[b] * rs;
        s_ac[0][b] = aa;
        s_ac[1][b] = e[b] - aa * mu;
    }
    __syncthreads();
    #pragma unroll
    for (int k = 0; k < NR; k++)
        out_t[k * NB + b] = s_ac[0][k] * v[k] + s_ac[1][k];
}

// ---------------------------------------------------------------------------
// Input BN: coalesced tiled read of x (256 x 5048), per-column stats, write
// normalized feature-major gene_n / drug_n. 32 cols per block, LDS transpose.
// ---------------------------------------------------------------------------
__global__ void k_in_bn(const float* __restrict__ x,
                        const float* __restrict__ gg, const float* __restrict__ eg,
                        const float* __restrict__ gd, const float* __restrict__ ed,
                        float* __restrict__ gene_n, float* __restrict__ drug_n) {
    __shared__ float tile[32 * 257];
    __shared__ float red1[8][33], red2[8][33];
    __shared__ float s_a[32], s_c[32];
    int t = threadIdx.x;
    int tx = t & 31, ty = t >> 5;
    int c0 = blockIdx.x * 32;
    int c = c0 + tx;
    bool valid = c < XW;
    float s1 = 0.f, s2 = 0.f;
    #pragma unroll 4
    for (int i = 0; i < 32; i++) {
        int r = ty * 32 + i;
        float v = valid ? x[(size_t)r * XW + c] : 0.f;
        tile[tx * 257 + r] = v;
        s1 += v; s2 += v * v;
    }
    red1[ty][tx] = s1; red2[ty][tx] = s2;
    __syncthreads();
    if (t < 32) {
        float t1 = 0.f, t2 = 0.f;
        #pragma unroll
        for (int k = 0; k < 8; k++) { t1 += red1[k][t]; t2 += red2[k][t]; }
        float mu  = t1 * (1.0f / 256.0f);
        float var = t2 * (1.0f / 256.0f) - mu * mu;
        float rs  = rsqrtf(var + EPSF);
        int col = c0 + t;
        float gv = 0.f, ev = 0.f;
        if (col < GENE)      { gv = gg[col];        ev = eg[col]; }
        else if (col < XW)   { gv = gd[col - GENE]; ev = ed[col - GENE]; }
        float aa = gv * rs;
        s_a[t] = aa; s_c[t] = ev - aa * mu;
    }
    __syncthreads();
    for (int cc = 0; cc < 32; cc++) {
        int col = c0 + cc;
        if (col >= XW) break;
        float w = s_a[cc] * tile[cc * 257 + t] + s_c[cc];
        if (col < GENE) gene_n[(size_t)col * NB + t] = w;
        else            drug_n[(size_t)(col - GENE) * NB + t] = w;
    }
}

// ---------------------------------------------------------------------------
// Sparse layer 0: term t has 30 gene cols x 6 rows. Writes normalized h1n.
// ---------------------------------------------------------------------------
__global__ void k_splin0(const float* __restrict__ gene_n,
                         const int* __restrict__ cols0, const float* __restrict__ w0,
                         const float* __restrict__ b0,
                         const float* __restrict__ g1, const float* __restrict__ e1,
                         float* __restrict__ h1n) {
    int t = blockIdx.x, b = threadIdx.x;
    float acc[6] = {0.f, 0.f, 0.f, 0.f, 0.f, 0.f};
    int base = t * 180;
    for (int i = 0; i < 30; i++) {
        int ei = base + i * 6;
        int cc = cols0[ei];
        float v = gene_n[(size_t)cc * NB + b];
        #pragma unroll
        for (int k = 0; k < 6; k++) acc[k] += v * w0[ei + k];
    }
    float v6[6];
    #pragma unroll
    for (int k = 0; k < 6; k++) v6[k] = tanhf(acc[k] + b0[t * 6 + k]);
    bn_fold_write<6>(v6, b, g1 + t * 6, e1 + t * 6, h1n + (size_t)t * 6 * NB);
}

// ---------------------------------------------------------------------------
// Sparse layer 1: out term o = sum of 5 children, each a 6x6 dense block.
// Input already normalized. Writes normalized h2n.
// ---------------------------------------------------------------------------
__global__ void k_splin1(const float* __restrict__ h1n,
                         const int* __restrict__ cols1, const float* __restrict__ w1,
                         const float* __restrict__ b1,
                         const float* __restrict__ g2, const float* __restrict__ e2,
                         float* __restrict__ h2n) {
    int o = blockIdx.x, b = threadIdx.x;
    float acc[6] = {0.f, 0.f, 0.f, 0.f, 0.f, 0.f};
    for (int pi = 0; pi < 5; pi++) {
        int qb = (o * 5 + pi) * 36;
        #pragma unroll
        for (int j = 0; j < 6; j++) {
            int cc = cols1[qb + j];
            float v = h1n[(size_t)cc * NB + b];
            #pragma unroll
            for (int i = 0; i < 6; i++) acc[i] += v * w1[qb + i * 6 + j];
        }
    }
    float v6[6];
    #pragma unroll
    for (int i = 0; i < 6; i++) v6[i] = tanhf(acc[i] + b1[o * 6 + i]);
    bn_fold_write<6>(v6, b, g2 + o * 6, e2 + o * 6, h2n + (size_t)o * 6 * NB);
}

// ---------------------------------------------------------------------------
// Sparse layer 2 (dense 24 x 2400): stage A, 24 kf x 16 chunks of 25 terms.
// ---------------------------------------------------------------------------
__global__ void k_splin2_part(const float* __restrict__ h2n,
                              const float* __restrict__ w2,
                              float* __restrict__ part2) {
    int kf = blockIdx.x >> 4, ch = blockIdx.x & 15, b = threadIdx.x;
    float acc = 0.f;
    int t0 = ch * 25;
    for (int t = t0; t < t0 + 25; t++) {
        const float* wrow = w2 + t * 144 + kf * 6;
        #pragma unroll
        for (int j = 0; j < 6; j++)
            acc += h2n[(size_t)(t * 6 + j) * NB + b] * wrow[j];
    }
    part2[(size_t)blockIdx.x * NB + b] = acc;
}

__global__ void k_splin2_fin(const float* __restrict__ part2,
                             const float* __restrict__ b2,
                             const float* __restrict__ gf, const float* __restrict__ ef,
                             float* __restrict__ fbn) {
    int kf = blockIdx.x, b = threadIdx.x;
    float acc = b2[kf];
    #pragma unroll
    for (int ch = 0; ch < 16; ch++) acc += part2[(size_t)(kf * 16 + ch) * NB + b];
    float v[1] = { tanhf(acc) };
    bn_fold_write<1>(v, b, gf + kf, ef + kf, fbn + (size_t)kf * NB);
}

// ---------------------------------------------------------------------------
// Drug layer 1 (2048 -> 128): stage A, 32 row-groups of 4 x 8 col-chunks.
// ---------------------------------------------------------------------------
__global__ void k_dense1_part(const float* __restrict__ drug_n,
                              const float* __restrict__ Wd1,
                              float* __restrict__ part1) {
    int jg = blockIdx.x >> 3, ch = blockIdx.x & 7, b = threadIdx.x;
    int j0 = jg * 4, c0 = ch * 256;
    float acc[4] = {0.f, 0.f, 0.f, 0.f};
    for (int c = c0; c < c0 + 256; c++) {
        float v = drug_n[(size_t)c * NB + b];
        #pragma unroll
        for (int jj = 0; jj < 4; jj++) acc[jj] += v * Wd1[(size_t)(j0 + jj) * DRUGW + c];
    }
    #pragma unroll
    for (int jj = 0; jj < 4; jj++)
        part1[(size_t)((j0 + jj) * 8 + ch) * NB + b] = acc[jj];
}

__global__ void k_dense1_fin(const float* __restrict__ part1,
                             const float* __restrict__ bd1,
                             const float* __restrict__ gd2, const float* __restrict__ ed2,
                             float* __restrict__ d1n) {
    int j = blockIdx.x, b = threadIdx.x;
    float acc = bd1[j];
    #pragma unroll
    for (int ch = 0; ch < 8; ch++) acc += part1[(size_t)(j * 8 + ch) * NB + b];
    float v[1] = { tanhf(acc) };
    bn_fold_write<1>(v, b, gd2 + j, ed2 + j, d1n + (size_t)j * NB);
}

// ---------------------------------------------------------------------------
// Small dense on normalized input: out = tanh(in_n @ W.T + bias), then BN-fold.
// ---------------------------------------------------------------------------
template<int JPB>
__global__ void k_dense_n(const float* __restrict__ in_n,
                          const float* __restrict__ W, const float* __restrict__ bias,
                          int ncols,
                          const float* __restrict__ g, const float* __restrict__ e,
                          float* __restrict__ out_n) {
    int j0 = blockIdx.x * JPB, b = threadIdx.x;
    float acc[JPB];
    #pragma unroll
    for (int jj = 0; jj < JPB; jj++) acc[jj] = 0.f;
    for (int c = 0; c < ncols; c++) {
        float v = in_n[(size_t)c * NB + b];
        #pragma unroll
        for (int jj = 0; jj < JPB; jj++) acc[jj] += v * W[(size_t)(j0 + jj) * ncols + c];
    }
    float v[JPB];
    #pragma unroll
    for (int jj = 0; jj < JPB; jj++) v[jj] = tanhf(acc[jj] + bias[j0 + jj]);
    bn_fold_write<JPB>(v, b, g + j0, e + j0, out_n + (size_t)j0 * NB);
}

// ---------------------------------------------------------------------------
// Head: out = tanh(o1n @ Wa.T + ba) * Wo + bo   (o1n already normalized)
// ---------------------------------------------------------------------------
__global__ void k_final(const float* __restrict__ o1n,
                        const float* __restrict__ Wa, const float* __restrict__ ba,
                        const float* __restrict__ Wo, const float* __restrict__ bo,
                        float* __restrict__ out) {
    int b = threadIdx.x;
    float acc = ba[0];
    #pragma unroll
    for (int j = 0; j < 64; j++) acc += o1n[(size_t)j * NB + b] * Wa[j];
    out[b] = tanhf(acc) * Wo[0] + bo[0];
}

extern "C" void kernel_launch(void* const* d_in, const int* in_sizes, int n_in,
                              void* d_out, int out_size, void* d_ws, size_t ws_size,
                              hipStream_t stream) {
    const float* x    = (const float*)d_in[0];
    const int*   cols0 = (const int*)d_in[2];
    const float* w0   = (const float*)d_in[3];
    const float* b0   = (const float*)d_in[4];
    const int*   cols1 = (const int*)d_in[6];
    const float* w1   = (const float*)d_in[7];
    const float* b1   = (const float*)d_in[8];
    const float* w2   = (const float*)d_in[11];
    const float* b2   = (const float*)d_in[12];
    const float* gg   = (const float*)d_in[13];
    const float* eg   = (const float*)d_in[14];
    const float* g1   = (const float*)d_in[15];
    const float* e1   = (const float*)d_in[16];
    const float* g2   = (const float*)d_in[17];
    const float* e2   = (const float*)d_in[18];
    const float* Wd1  = (const float*)d_in[19];
    const float* bd1  = (const float*)d_in[20];
    const float* gd1  = (const float*)d_in[21];
    const float* ed1  = (const float*)d_in[22];
    const float* Wd2  = (const float*)d_in[23];
    const float* bd2  = (const float*)d_in[24];
    const float* gd2  = (const float*)d_in[25];
    const float* ed2  = (const float*)d_in[26];
    const float* Wd3  = (const float*)d_in[27];
    const float* bd3  = (const float*)d_in[28];
    const float* gd3  = (const float*)d_in[29];
    const float* ed3  = (const float*)d_in[30];
    const float* gf   = (const float*)d_in[31];
    const float* ef   = (const float*)d_in[32];
    const float* Wf   = (const float*)d_in[33];
    const float* bf   = (const float*)d_in[34];
    const float* ga   = (const float*)d_in[35];
    const float* ea   = (const float*)d_in[36];
    const float* Wa   = (const float*)d_in[37];
    const float* ba   = (const float*)d_in[38];
    const float* Wo   = (const float*)d_in[39];
    const float* bo   = (const float*)d_in[40];
    float* out = (float*)d_out;

    float* W = (float*)d_ws;
    float* gene_n = W;                        // 3000*256
    float* drug_n = gene_n + 3000 * NB;       // 2048*256
    float* h1n    = drug_n + 2048 * NB;       // 9000*256
    float* h2n    = h1n    + 9000 * NB;       // 2400*256
    float* fbn    = h2n    + 2400 * NB;       // 56*256   (rows 0..23 splin2, 24..55 drug3)
    float* d1n    = fbn    + 56 * NB;         // 128*256
    float* d2n    = d1n    + 128 * NB;        // 64*256
    float* o1n    = d2n    + 64 * NB;         // 64*256
    float* part2  = o1n    + 64 * NB;         // 24*16*256
    float* part1  = part2  + 24 * 16 * NB;    // 128*8*256

    // input BN (gene with gg/eg, drug with gd1/ed1), transposed to feature-major
    k_in_bn<<<(XW + 31) / 32, 256, 0, stream>>>(x, gg, eg, gd1, ed1, gene_n, drug_n);

    // gene path (all BN folded into producers)
    k_splin0<<<1500, 256, 0, stream>>>(gene_n, cols0, w0, b0, g1, e1, h1n);
    k_splin1<<<400, 256, 0, stream>>>(h1n, cols1, w1, b1, g2, e2, h2n);
    k_splin2_part<<<24 * 16, 256, 0, stream>>>(h2n, w2, part2);
    k_splin2_fin<<<24, 256, 0, stream>>>(part2, b2, gf, ef, fbn);

    // drug path
    k_dense1_part<<<32 * 8, 256, 0, stream>>>(drug_n, Wd1, part1);
    k_dense1_fin<<<128, 256, 0, stream>>>(part1, bd1, gd2, ed2, d1n);
    k_dense_n<8><<<8, 256, 0, stream>>>(d1n, Wd2, bd2, 128, gd3, ed3, d2n);
    k_dense_n<8><<<4, 256, 0, stream>>>(d2n, Wd3, bd3, 64, gf + 24, ef + 24, fbn + 24 * NB);

    // head
    k_dense_n<8><<<8, 256, 0, stream>>>(fbn, Wf, bf, 56, ga, ea, o1n);
    k_final<<<1, 256, 0, stream>>>(o1n, Wa, ba, Wo, bo, out);
}